// Round 10
// baseline (236.492 us; speedup 1.0000x reference)
//
#include <hip/hip_runtime.h>
#include <hip/hip_bf16.h>

typedef __bf16 bf16_t;
typedef __bf16 bf16x2 __attribute__((ext_vector_type(2)));
typedef __bf16 bf16x4 __attribute__((ext_vector_type(4)));
typedef __bf16 bf16x8 __attribute__((ext_vector_type(8)));
typedef short s16x4 __attribute__((ext_vector_type(4)));
typedef float f32x2 __attribute__((ext_vector_type(2)));
typedef float f32x4 __attribute__((ext_vector_type(4)));
typedef unsigned int u32;

#define MFMA16(a, b, c) __builtin_amdgcn_mfma_f32_16x16x32_bf16(a, b, c, 0, 0, 0)

// PV uses 16x16x16 so the S^T C-layout quartets feed B directly (no bpermute).
static __device__ inline f32x4 mfma_pv(bf16x4 a, bf16x4 b, f32x4 c) {
#if __has_builtin(__builtin_amdgcn_mfma_f32_16x16x16_bf16)
    return __builtin_amdgcn_mfma_f32_16x16x16_bf16(a, b, c, 0, 0, 0);
#elif __has_builtin(__builtin_amdgcn_mfma_f32_16x16x16bf16_1k)
    return __builtin_amdgcn_mfma_f32_16x16x16bf16_1k(
        __builtin_bit_cast(s16x4, a), __builtin_bit_cast(s16x4, b), c, 0, 0, 0);
#else
    f32x4 d;
    asm volatile("v_mfma_f32_16x16x16_bf16 %0, %1, %2, %3"
                 : "=v"(d) : "v"(a), "v"(b), "v"(c));
    return d;
#endif
}

static __device__ inline float fast_exp2(float x) {
#if __has_builtin(__builtin_amdgcn_exp2f)
    return __builtin_amdgcn_exp2f(x);
#else
    return exp2f(x);
#endif
}

__device__ inline float ldf(const void* p, int i, int f32) {
    return f32 ? ((const float*)p)[i] : (float)((const bf16_t*)p)[i];
}

__device__ inline void ln8(float* p, const void* g, const void* b, int f32) {
    float m = 0.f;
#pragma unroll
    for (int i = 0; i < 8; ++i) m += p[i];
    m *= 0.125f;
    float v = 0.f;
#pragma unroll
    for (int i = 0; i < 8; ++i) { float d = p[i] - m; v += d * d; }
    v *= 0.125f;
    float r = rsqrtf(v + 1e-5f);
#pragma unroll
    for (int i = 0; i < 8; ++i)
        p[i] = fmaxf((p[i] - m) * r * ldf(g, i, f32) + ldf(b, i, f32), 0.f);
}

// ---------------------------------------------------------------------------
// prep_all: probe + weight-fold + DPB MLP + conv_norm (R3 structure).
//   bid 0..95   : fold qkv_w rows (4 rows/block, one per wave)
//   bid 96..99  : DynamicPosBias MLP rows (256/block)
//   bid >= 100  : conv_norm (16 tokens/block), only launched when ws allows
// ---------------------------------------------------------------------------
__global__ __launch_bounds__(256) void prep_all(
    const void* __restrict__ xv, bf16_t* __restrict__ xn,
    int* __restrict__ flags,
    const void* __restrict__ qw, const void* __restrict__ qb,
    const void* __restrict__ ng, const void* __restrict__ nb,
    bf16_t* __restrict__ Wp, float* __restrict__ uu, float* __restrict__ tt,
    const void* __restrict__ ppw, const void* __restrict__ ppb,
    const void* __restrict__ l1g, const void* __restrict__ l1b,
    const void* __restrict__ f1w, const void* __restrict__ f1b,
    const void* __restrict__ l2g, const void* __restrict__ l2b,
    const void* __restrict__ f2w, const void* __restrict__ f2b,
    const void* __restrict__ l3g, const void* __restrict__ l3b,
    const void* __restrict__ f3w, const void* __restrict__ f3b,
    float* __restrict__ pos) {
    const int tid = threadIdx.x;
    const int lane = tid & 63;
    u32 pv = ((const u32*)xv)[lane];
    int pf = (((pv >> 7) & 0xFFu) >= 0x90u) || (((pv >> 23) & 0xFFu) >= 0x90u);
    const int f32 = __any(pf) ? 1 : 0;
    const int bid = blockIdx.x;
    if (bid == 0 && tid == 0) flags[0] = f32;

    if (bid >= 100) {
        const int sub = lane & 15;
        const int t = (bid - 100) * 16 + (tid >> 6) * 4 + (lane >> 4);
        float f[8];
        if (f32) {
            const float* p = (const float*)xv + t * 128 + sub * 8;
            f32x4 a = *(const f32x4*)p;
            f32x4 b = *(const f32x4*)(p + 4);
#pragma unroll
            for (int e = 0; e < 4; ++e) { f[e] = a[e]; f[4 + e] = b[e]; }
        } else {
            bf16x8 v = *(const bf16x8*)((const bf16_t*)xv + t * 128 + sub * 8);
#pragma unroll
            for (int e = 0; e < 8; ++e) f[e] = (float)v[e];
        }
        float s = 0.f, s2 = 0.f;
#pragma unroll
        for (int e = 0; e < 8; ++e) { s += f[e]; s2 += f[e] * f[e]; }
#pragma unroll
        for (int off = 8; off >= 1; off >>= 1) {
            s += __shfl_xor(s, off, 64);
            s2 += __shfl_xor(s2, off, 64);
        }
        float mu = s * (1.f / 128.f);
        float r = rsqrtf(s2 * (1.f / 128.f) - mu * mu + 1e-5f);
        bf16x8 h;
#pragma unroll
        for (int e = 0; e < 8; ++e) h[e] = (bf16_t)((f[e] - mu) * r);
        *(bf16x8*)(xn + t * 128 + sub * 8) = h;
        return;
    }

    if (bid < 96) {
        int j = bid * 4 + (tid >> 6);
        int l = lane;
        float g0 = ldf(ng, l, f32),  g1 = ldf(ng, l + 64, f32);
        float b0 = ldf(nb, l, f32),  b1 = ldf(nb, l + 64, f32);
        float w0 = ldf(qw, j * 128 + l, f32), w1 = ldf(qw, j * 128 + l + 64, f32);
        float wg0 = w0 * g0, wg1 = w1 * g1;
        Wp[j * 128 + l] = (bf16_t)wg0;
        Wp[j * 128 + l + 64] = (bf16_t)wg1;
        float su = wg0 + wg1;
        float st = w0 * b0 + w1 * b1;
#pragma unroll
        for (int off = 32; off >= 1; off >>= 1) {
            su += __shfl_xor(su, off, 64);
            st += __shfl_xor(st, off, 64);
        }
        if (l == 0) { uu[j] = su; tt[j] = st + ldf(qb, j, f32); }
        return;
    }

    int r = (bid - 96) * 256 + tid;
    if (r >= 961) return;
    float bh = (float)(r / 31) - 15.f;
    float bw = (float)(r % 31) - 15.f;
    float p[8], q[8];
#pragma unroll
    for (int i = 0; i < 8; ++i)
        p[i] = ldf(ppw, i * 2, f32) * bh + ldf(ppw, i * 2 + 1, f32) * bw + ldf(ppb, i, f32);
    ln8(p, l1g, l1b, f32);
#pragma unroll
    for (int o = 0; o < 8; ++o) {
        float s = ldf(f1b, o, f32);
#pragma unroll
        for (int i = 0; i < 8; ++i) s += p[i] * ldf(f1w, o * 8 + i, f32);
        q[o] = s;
    }
    ln8(q, l2g, l2b, f32);
#pragma unroll
    for (int o = 0; o < 8; ++o) {
        float s = ldf(f2b, o, f32);
#pragma unroll
        for (int i = 0; i < 8; ++i) s += q[i] * ldf(f2w, o * 8 + i, f32);
        p[o] = s;
    }
    ln8(p, l3g, l3b, f32);
#pragma unroll
    for (int o = 0; o < 4; ++o) {
        float s = ldf(f3b, o, f32);
#pragma unroll
        for (int i = 0; i < 8; ++i) s += p[i] * ldf(f3w, o * 8 + i, f32);
        pos[r * 4 + o] = s;
    }
}

// ---------------------------------------------------------------------------
// win_attn: one block per (window, head); 4 waves x 64 q-tokens. QKV in two
// passes: A = {q,K} fused (acc 64 regs), B = V (acc 32 regs) -> no spill at
// the (256,3) cap; af reloaded in pass B from L1/L2-hot xn. S^T = K Q^T;
// PV via 16x16x16 MFMA consuming P quartets natively. exp2-domain softmax
// with padded f32 bias rows. XCD-swizzled bid. ONE barrier.
// ---------------------------------------------------------------------------
template <int XN>
__global__ __launch_bounds__(256, 3) void win_attn(
    const void* __restrict__ xv, const bf16_t* __restrict__ xnp,
    const bf16_t* __restrict__ Wp, const float* __restrict__ uu,
    const float* __restrict__ tt, const float* __restrict__ posg,
    const int* __restrict__ flags, void* __restrict__ outv) {
    __shared__ __align__(16) bf16_t k_s[256 * 40];   // q-stage then K [token][d]
    __shared__ __align__(16) bf16_t vT_s[32 * 264];  // V^T [d][token]
    __shared__ __align__(16) float pos_f[31 * 32];   // bias rows padded to 32 f32
    __shared__ float mu_s[XN ? 2 : 256];
    __shared__ float r_s[XN ? 2 : 256];

    const int f32 = flags[0];
    const int tid = threadIdx.x;
    const int lane = tid & 63;
    const int w = tid >> 6;
    const int l15 = lane & 15;
    const int quad = lane >> 4;
    // XCD swizzle: heads of a window map to the same XCD (bid mod 8 equal).
    const int bid = blockIdx.x;
    const int head = (bid >> 3) & 3;
    const int wi = (bid & 7) | ((bid >> 5) << 3);
    const int bi = wi >> 8;
    const int wh = (wi >> 4) & 15, ww = wi & 15;
    const int xbase = bi * (256 * 256 * 128);

    // bias rows padded to stride 32, premultiplied by log2(e)
    for (int r = tid; r < 961; r += 256)
        pos_f[(r / 31) * 32 + (r % 31)] = posg[r * 4 + head] * 1.4426950408889634f;

    if (!XN) {
#pragma unroll
        for (int it = 0; it < 4; ++it) {
            int i = w * 64 + it * 16 + (lane >> 2);
            int gi = xbase + ((wh * 16 + (i >> 4)) * 256 + ww * 16 + (i & 15)) * 128;
            float s = 0.f, s2 = 0.f;
            if (f32) {
                const f32x4* p4 = (const f32x4*)((const float*)xv + gi);
#pragma unroll
                for (int c = 0; c < 4; ++c) {
                    f32x4 a = p4[(c * 4 + (lane & 3)) * 2];
                    f32x4 b = p4[(c * 4 + (lane & 3)) * 2 + 1];
#pragma unroll
                    for (int e = 0; e < 4; ++e) { s += a[e] + b[e]; s2 += a[e] * a[e] + b[e] * b[e]; }
                }
            } else {
                const bf16_t* p = (const bf16_t*)xv + gi;
#pragma unroll
                for (int c = 0; c < 4; ++c) {
                    bf16x8 v = *(const bf16x8*)(p + (c * 4 + (lane & 3)) * 8);
#pragma unroll
                    for (int e = 0; e < 8; ++e) { float f = (float)v[e]; s += f; s2 += f * f; }
                }
            }
            s  += __shfl_xor(s, 1, 4);  s  += __shfl_xor(s, 2, 4);
            s2 += __shfl_xor(s2, 1, 4); s2 += __shfl_xor(s2, 2, 4);
            if ((lane & 3) == 0) {
                float mu = s * (1.f / 128.f);
                mu_s[i] = mu;
                r_s[i] = rsqrtf(s2 * (1.f / 128.f) - mu * mu + 1e-5f);
            }
        }
    }

    int axi[4];
#pragma unroll
    for (int mt = 0; mt < 4; ++mt) {
        int i = w * 64 + mt * 16 + l15;
        axi[mt] = xbase + ((wh * 16 + (i >> 4)) * 256 + ww * 16 + (i & 15)) * 128;
    }
    const float qscale = 0.25503486f;  // log2(e)/sqrt(32)
    bf16x8 qB[4];
    const bf16_t* bwBase = Wp + (head * 32 + l15) * 128;

    // ================= Pass A: q (sel 0) + K (sel 1), acc 64 regs =========
    {
        f32x4 acc[2][2][4];
#pragma unroll
        for (int s2 = 0; s2 < 2; ++s2)
#pragma unroll
            for (int nt = 0; nt < 2; ++nt)
#pragma unroll
                for (int mt = 0; mt < 4; ++mt) acc[s2][nt][mt] = f32x4{0.f, 0.f, 0.f, 0.f};
#pragma unroll
        for (int ks = 0; ks < 4; ++ks) {
            int ko = ks * 32 + quad * 8;
            bf16x8 af[4];
            if (XN) {
#pragma unroll
                for (int mt = 0; mt < 4; ++mt)
                    af[mt] = *(const bf16x8*)(xnp + axi[mt] + ko);
            } else if (f32) {
#pragma unroll
                for (int mt = 0; mt < 4; ++mt) {
                    const float* pp = (const float*)xv + axi[mt] + ko;
                    f32x4 u0 = *(const f32x4*)pp;
                    f32x4 u1 = *(const f32x4*)(pp + 4);
                    bf16x8 t;
#pragma unroll
                    for (int e = 0; e < 4; ++e) { t[e] = (bf16_t)u0[e]; t[e + 4] = (bf16_t)u1[e]; }
                    af[mt] = t;
                }
            } else {
#pragma unroll
                for (int mt = 0; mt < 4; ++mt)
                    af[mt] = *(const bf16x8*)((const bf16_t*)xv + axi[mt] + ko);
            }
#pragma unroll
            for (int s2 = 0; s2 < 2; ++s2) {
                bf16x8 b0 = *(const bf16x8*)(bwBase + s2 * (128 * 128) + ko);
                bf16x8 b1 = *(const bf16x8*)(bwBase + s2 * (128 * 128) + 16 * 128 + ko);
#pragma unroll
                for (int mt = 0; mt < 4; ++mt) {
                    acc[s2][0][mt] = MFMA16(af[mt], b0, acc[s2][0][mt]);
                    acc[s2][1][mt] = MFMA16(af[mt], b1, acc[s2][1][mt]);
                }
            }
        }
        float tj[2][2], uj[2][2];
#pragma unroll
        for (int s2 = 0; s2 < 2; ++s2)
#pragma unroll
            for (int nt = 0; nt < 2; ++nt) {
                tj[s2][nt] = tt[s2 * 128 + head * 32 + nt * 16 + l15];
                uj[s2][nt] = XN ? 0.f : uu[s2 * 128 + head * 32 + nt * 16 + l15];
            }
        // fixup sel 0 (q) -> k_s, then read qB, then sel 1 (K) overwrites.
#pragma unroll
        for (int s2 = 0; s2 < 2; ++s2) {
#pragma unroll
            for (int mt = 0; mt < 4; ++mt) {
                int tok0 = w * 64 + mt * 16 + quad * 4;
#pragma unroll
                for (int nt = 0; nt < 2; ++nt) {
                    int d = nt * 16 + l15;
#pragma unroll
                    for (int rg = 0; rg < 4; ++rg) {
                        float v;
                        if (XN) v = acc[s2][nt][mt][rg] + tj[s2][nt];
                        else {
                            int token = tok0 + rg;
                            v = r_s[token] * (acc[s2][nt][mt][rg] - mu_s[token] * uj[s2][nt]) + tj[s2][nt];
                        }
                        k_s[(tok0 + rg) * 40 + d] = (bf16_t)(s2 == 0 ? v * qscale : v);
                    }
                }
            }
            if (s2 == 0) {
#pragma unroll
                for (int qt = 0; qt < 4; ++qt)
                    qB[qt] = *(const bf16x8*)(k_s + (w * 64 + qt * 16 + l15) * 40 + quad * 8);
            }
        }
    }

    // ================= Pass B: V (sel 2), acc 32 regs =====================
    {
        f32x4 acc[2][4];
#pragma unroll
        for (int nt = 0; nt < 2; ++nt)
#pragma unroll
            for (int mt = 0; mt < 4; ++mt) acc[nt][mt] = f32x4{0.f, 0.f, 0.f, 0.f};
#pragma unroll
        for (int ks = 0; ks < 4; ++ks) {
            int ko = ks * 32 + quad * 8;
            bf16x8 af[4];
            if (XN) {
#pragma unroll
                for (int mt = 0; mt < 4; ++mt)
                    af[mt] = *(const bf16x8*)(xnp + axi[mt] + ko);
            } else if (f32) {
#pragma unroll
                for (int mt = 0; mt < 4; ++mt) {
                    const float* pp = (const float*)xv + axi[mt] + ko;
                    f32x4 u0 = *(const f32x4*)pp;
                    f32x4 u1 = *(const f32x4*)(pp + 4);
                    bf16x8 t;
#pragma unroll
                    for (int e = 0; e < 4; ++e) { t[e] = (bf16_t)u0[e]; t[e + 4] = (bf16_t)u1[e]; }
                    af[mt] = t;
                }
            } else {
#pragma unroll
                for (int mt = 0; mt < 4; ++mt)
                    af[mt] = *(const bf16x8*)((const bf16_t*)xv + axi[mt] + ko);
            }
            bf16x8 b0 = *(const bf16x8*)(bwBase + 2 * (128 * 128) + ko);
            bf16x8 b1 = *(const bf16x8*)(bwBase + 2 * (128 * 128) + 16 * 128 + ko);
#pragma unroll
            for (int mt = 0; mt < 4; ++mt) {
                acc[0][mt] = MFMA16(af[mt], b0, acc[0][mt]);
                acc[1][mt] = MFMA16(af[mt], b1, acc[1][mt]);
            }
        }
        float tj[2], uj[2];
#pragma unroll
        for (int nt = 0; nt < 2; ++nt) {
            tj[nt] = tt[2 * 128 + head * 32 + nt * 16 + l15];
            uj[nt] = XN ? 0.f : uu[2 * 128 + head * 32 + nt * 16 + l15];
        }
#pragma unroll
        for (int mt = 0; mt < 4; ++mt) {
            int tok0 = w * 64 + mt * 16 + quad * 4;
#pragma unroll
            for (int nt = 0; nt < 2; ++nt) {
                int d = nt * 16 + l15;
                float vv[4];
#pragma unroll
                for (int rg = 0; rg < 4; ++rg) {
                    if (XN) vv[rg] = acc[nt][mt][rg] + tj[nt];
                    else {
                        int token = tok0 + rg;
                        vv[rg] = r_s[token] * (acc[nt][mt][rg] - mu_s[token] * uj[nt]) + tj[nt];
                    }
                }
                bf16x4 h = { (bf16_t)vv[0], (bf16_t)vv[1], (bf16_t)vv[2], (bf16_t)vv[3] };
                *(bf16x4*)(vT_s + d * 264 + tok0) = h;
            }
        }
    }
    __syncthreads();  // K / V^T / pos_f visible to all waves

    // ---- kb loop: S^T = K Q^T; P quartets feed 16x16x16 PV directly ----
    f32x4 Oa[2][4];
#pragma unroll
    for (int np = 0; np < 2; ++np)
#pragma unroll
        for (int qt = 0; qt < 4; ++qt) Oa[np][qt] = f32x4{0.f, 0.f, 0.f, 0.f};
    float lsum[4] = {0.f, 0.f, 0.f, 0.f};

    const f32x4 zero4 = {0.f, 0.f, 0.f, 0.f};
    const int pcol = l15 + 12 - quad * 4;  // base col of this lane's 4 bias f32s

#pragma unroll 2
    for (int kb = 0; kb < 8; ++kb) {
        bf16x4 pF[2][4];  // [nt][qt] native P quartets = PV B-frags
#pragma unroll
        for (int nt = 0; nt < 2; ++nt) {
            bf16x8 kf = *(const bf16x8*)(k_s + (kb * 32 + nt * 16 + l15) * 40 + quad * 8);
            f32x4 S[4];
            __builtin_amdgcn_s_setprio(1);
#pragma unroll
            for (int qt = 0; qt < 4; ++qt) S[qt] = MFMA16(kf, qB[qt], zero4);
            __builtin_amdgcn_s_setprio(0);
#pragma unroll
            for (int qt = 0; qt < 4; ++qt) {
                // padded-row bias: 4 consecutive f32 (rg uses pr[3-rg])
                const float* pr = pos_f + (w * 4 + qt - kb * 2 - nt + 15) * 32 + pcol;
                float b0_ = pr[0], b1_ = pr[1], b2_ = pr[2], b3_ = pr[3];
                float p[4];
                p[0] = fast_exp2(S[qt][0] + b3_);
                p[1] = fast_exp2(S[qt][1] + b2_);
                p[2] = fast_exp2(S[qt][2] + b1_);
                p[3] = fast_exp2(S[qt][3] + b0_);
                lsum[qt] += (p[0] + p[1]) + (p[2] + p[3]);
                bf16x4 h = { (bf16_t)p[0], (bf16_t)p[1], (bf16_t)p[2], (bf16_t)p[3] };
                pF[nt][qt] = h;
            }
        }
#pragma unroll
        for (int np = 0; np < 2; ++np) {
            const bf16_t* vrow = vT_s + (np * 16 + l15) * 264 + kb * 32 + quad * 4;
            bf16x4 vf0 = *(const bf16x4*)vrow;         // nt=0 k-quartet
            bf16x4 vf1 = *(const bf16x4*)(vrow + 16);  // nt=1 k-quartet
            __builtin_amdgcn_s_setprio(1);
#pragma unroll
            for (int qt = 0; qt < 4; ++qt) {
                Oa[np][qt] = mfma_pv(vf0, pF[0][qt], Oa[np][qt]);
                Oa[np][qt] = mfma_pv(vf1, pF[1][qt], Oa[np][qt]);
            }
            __builtin_amdgcn_s_setprio(0);
        }
    }

    // ---- epilogue: reduce lsum, O/l + residual, store (qt-outer so both
    //      64B halves of each 128B line issue adjacently) ----
    float inv[4];
#pragma unroll
    for (int qt = 0; qt < 4; ++qt) {
        float l = lsum[qt];
        l += __shfl_xor(l, 16, 64);
        l += __shfl_xor(l, 32, 64);
        inv[qt] = 1.f / l;
    }
#pragma unroll
    for (int qt = 0; qt < 4; ++qt)
#pragma unroll
        for (int np = 0; np < 2; ++np) {
            int go = xbase + ((wh * 16 + w * 4 + qt) * 256 + ww * 16 + l15) * 128 +
                     head * 32 + np * 16 + quad * 4;
            if (f32) {
                f32x4 res = *(const f32x4*)((const float*)xv + go);
                f32x4 o;
#pragma unroll
                for (int rg = 0; rg < 4; ++rg) o[rg] = Oa[np][qt][rg] * inv[qt] + res[rg];
                *(f32x4*)((float*)outv + go) = o;
            } else {
                bf16x4 res = *(const bf16x4*)((const bf16_t*)xv + go);
                bf16x4 o;
#pragma unroll
                for (int rg = 0; rg < 4; ++rg)
                    o[rg] = (bf16_t)(Oa[np][qt][rg] * inv[qt] + (float)res[rg]);
                *(bf16x4*)((bf16_t*)outv + go) = o;
            }
        }
}

extern "C" void kernel_launch(void* const* d_in, const int* in_sizes, int n_in,
                              void* d_out, int out_size, void* d_ws, size_t ws_size,
                              hipStream_t stream) {
    const void* x   = d_in[0];
    const void* ng  = d_in[1];
    const void* nb  = d_in[2];
    const void* qw  = d_in[3];
    const void* qb  = d_in[4];
    const void* ppw = d_in[5];
    const void* ppb = d_in[6];
    const void* l1g = d_in[7];
    const void* l1b = d_in[8];
    const void* f1w = d_in[9];
    const void* f1b = d_in[10];
    const void* l2g = d_in[11];
    const void* l2b = d_in[12];
    const void* f2w = d_in[13];
    const void* f2b = d_in[14];
    const void* l3g = d_in[15];
    const void* l3b = d_in[16];
    const void* f3w = d_in[17];
    const void* f3b = d_in[18];

    char* ws = (char*)d_ws;
    int*    flags = (int*)ws;                 // @0, 16 B
    bf16_t* Wp    = (bf16_t*)(ws + 16);       // 98304 B
    float*  uu    = (float*)(ws + 98320);     // 1536 B
    float*  tt    = (float*)(ws + 99856);     // 1536 B
    float*  pos   = (float*)(ws + 101392);    // 15376 B
    bf16_t* xn    = (bf16_t*)(ws + 116768);   // 33554432 B
    const int use_xn = (ws_size >= 116768 + 33554432u) ? 1 : 0;

    int prep_grid = use_xn ? 8292 : 100;
    prep_all<<<dim3(prep_grid), dim3(256), 0, stream>>>(
        x, xn, flags, qw, qb, ng, nb, Wp, uu, tt,
        ppw, ppb, l1g, l1b, f1w, f1b, l2g, l2b, f2w, f2b, l3g, l3b,
        f3w, f3b, pos);
    if (use_xn)
        win_attn<1><<<dim3(2048), dim3(256), 0, stream>>>(x, xn, Wp, uu, tt, pos,
                                                          flags, d_out);
    else
        win_attn<0><<<dim3(2048), dim3(256), 0, stream>>>(x, xn, Wp, uu, tt, pos,
                                                          flags, d_out);
}

// Round 11
// 225.714 us; speedup vs baseline: 1.0478x; 1.0478x over previous
//
#include <hip/hip_runtime.h>
#include <hip/hip_bf16.h>

typedef __bf16 bf16_t;
typedef __bf16 bf16x2 __attribute__((ext_vector_type(2)));
typedef __bf16 bf16x4 __attribute__((ext_vector_type(4)));
typedef __bf16 bf16x8 __attribute__((ext_vector_type(8)));
typedef short s16x4 __attribute__((ext_vector_type(4)));
typedef float f32x2 __attribute__((ext_vector_type(2)));
typedef float f32x4 __attribute__((ext_vector_type(4)));
typedef unsigned int u32;

#define MFMA16(a, b, c) __builtin_amdgcn_mfma_f32_16x16x32_bf16(a, b, c, 0, 0, 0)

// PV uses 16x16x16 so the S^T C-layout quartets feed B directly (no bpermute).
static __device__ inline f32x4 mfma_pv(bf16x4 a, bf16x4 b, f32x4 c) {
#if __has_builtin(__builtin_amdgcn_mfma_f32_16x16x16_bf16)
    return __builtin_amdgcn_mfma_f32_16x16x16_bf16(a, b, c, 0, 0, 0);
#elif __has_builtin(__builtin_amdgcn_mfma_f32_16x16x16bf16_1k)
    return __builtin_amdgcn_mfma_f32_16x16x16bf16_1k(
        __builtin_bit_cast(s16x4, a), __builtin_bit_cast(s16x4, b), c, 0, 0, 0);
#else
    f32x4 d;
    asm volatile("v_mfma_f32_16x16x16_bf16 %0, %1, %2, %3"
                 : "=v"(d) : "v"(a), "v"(b), "v"(c));
    return d;
#endif
}

static __device__ inline float fast_exp2(float x) {
#if __has_builtin(__builtin_amdgcn_exp2f)
    return __builtin_amdgcn_exp2f(x);
#else
    return exp2f(x);
#endif
}

__device__ inline float ldf(const void* p, int i, int f32) {
    return f32 ? ((const float*)p)[i] : (float)((const bf16_t*)p)[i];
}

__device__ inline void ln8(float* p, const void* g, const void* b, int f32) {
    float m = 0.f;
#pragma unroll
    for (int i = 0; i < 8; ++i) m += p[i];
    m *= 0.125f;
    float v = 0.f;
#pragma unroll
    for (int i = 0; i < 8; ++i) { float d = p[i] - m; v += d * d; }
    v *= 0.125f;
    float r = rsqrtf(v + 1e-5f);
#pragma unroll
    for (int i = 0; i < 8; ++i)
        p[i] = fmaxf((p[i] - m) * r * ldf(g, i, f32) + ldf(b, i, f32), 0.f);
}

// ---------------------------------------------------------------------------
// prep_all: probe + weight-fold + DPB MLP + conv_norm (R3 structure).
//   bid 0..95   : fold qkv_w rows (4 rows/block, one per wave)
//   bid 96..99  : DynamicPosBias MLP rows (256/block)
//   bid >= 100  : conv_norm (16 tokens/block), only launched when ws allows
// ---------------------------------------------------------------------------
__global__ __launch_bounds__(256) void prep_all(
    const void* __restrict__ xv, bf16_t* __restrict__ xn,
    int* __restrict__ flags,
    const void* __restrict__ qw, const void* __restrict__ qb,
    const void* __restrict__ ng, const void* __restrict__ nb,
    bf16_t* __restrict__ Wp, float* __restrict__ uu, float* __restrict__ tt,
    const void* __restrict__ ppw, const void* __restrict__ ppb,
    const void* __restrict__ l1g, const void* __restrict__ l1b,
    const void* __restrict__ f1w, const void* __restrict__ f1b,
    const void* __restrict__ l2g, const void* __restrict__ l2b,
    const void* __restrict__ f2w, const void* __restrict__ f2b,
    const void* __restrict__ l3g, const void* __restrict__ l3b,
    const void* __restrict__ f3w, const void* __restrict__ f3b,
    float* __restrict__ pos) {
    const int tid = threadIdx.x;
    const int lane = tid & 63;
    u32 pv = ((const u32*)xv)[lane];
    int pf = (((pv >> 7) & 0xFFu) >= 0x90u) || (((pv >> 23) & 0xFFu) >= 0x90u);
    const int f32 = __any(pf) ? 1 : 0;
    const int bid = blockIdx.x;
    if (bid == 0 && tid == 0) flags[0] = f32;

    if (bid >= 100) {
        const int sub = lane & 15;
        const int t = (bid - 100) * 16 + (tid >> 6) * 4 + (lane >> 4);
        float f[8];
        if (f32) {
            const float* p = (const float*)xv + t * 128 + sub * 8;
            f32x4 a = *(const f32x4*)p;
            f32x4 b = *(const f32x4*)(p + 4);
#pragma unroll
            for (int e = 0; e < 4; ++e) { f[e] = a[e]; f[4 + e] = b[e]; }
        } else {
            bf16x8 v = *(const bf16x8*)((const bf16_t*)xv + t * 128 + sub * 8);
#pragma unroll
            for (int e = 0; e < 8; ++e) f[e] = (float)v[e];
        }
        float s = 0.f, s2 = 0.f;
#pragma unroll
        for (int e = 0; e < 8; ++e) { s += f[e]; s2 += f[e] * f[e]; }
#pragma unroll
        for (int off = 8; off >= 1; off >>= 1) {
            s += __shfl_xor(s, off, 64);
            s2 += __shfl_xor(s2, off, 64);
        }
        float mu = s * (1.f / 128.f);
        float r = rsqrtf(s2 * (1.f / 128.f) - mu * mu + 1e-5f);
        bf16x8 h;
#pragma unroll
        for (int e = 0; e < 8; ++e) h[e] = (bf16_t)((f[e] - mu) * r);
        *(bf16x8*)(xn + t * 128 + sub * 8) = h;
        return;
    }

    if (bid < 96) {
        int j = bid * 4 + (tid >> 6);
        int l = lane;
        float g0 = ldf(ng, l, f32),  g1 = ldf(ng, l + 64, f32);
        float b0 = ldf(nb, l, f32),  b1 = ldf(nb, l + 64, f32);
        float w0 = ldf(qw, j * 128 + l, f32), w1 = ldf(qw, j * 128 + l + 64, f32);
        float wg0 = w0 * g0, wg1 = w1 * g1;
        Wp[j * 128 + l] = (bf16_t)wg0;
        Wp[j * 128 + l + 64] = (bf16_t)wg1;
        float su = wg0 + wg1;
        float st = w0 * b0 + w1 * b1;
#pragma unroll
        for (int off = 32; off >= 1; off >>= 1) {
            su += __shfl_xor(su, off, 64);
            st += __shfl_xor(st, off, 64);
        }
        if (l == 0) { uu[j] = su; tt[j] = st + ldf(qb, j, f32); }
        return;
    }

    int r = (bid - 96) * 256 + tid;
    if (r >= 961) return;
    float bh = (float)(r / 31) - 15.f;
    float bw = (float)(r % 31) - 15.f;
    float p[8], q[8];
#pragma unroll
    for (int i = 0; i < 8; ++i)
        p[i] = ldf(ppw, i * 2, f32) * bh + ldf(ppw, i * 2 + 1, f32) * bw + ldf(ppb, i, f32);
    ln8(p, l1g, l1b, f32);
#pragma unroll
    for (int o = 0; o < 8; ++o) {
        float s = ldf(f1b, o, f32);
#pragma unroll
        for (int i = 0; i < 8; ++i) s += p[i] * ldf(f1w, o * 8 + i, f32);
        q[o] = s;
    }
    ln8(q, l2g, l2b, f32);
#pragma unroll
    for (int o = 0; o < 8; ++o) {
        float s = ldf(f2b, o, f32);
#pragma unroll
        for (int i = 0; i < 8; ++i) s += q[i] * ldf(f2w, o * 8 + i, f32);
        p[o] = s;
    }
    ln8(p, l3g, l3b, f32);
#pragma unroll
    for (int o = 0; o < 4; ++o) {
        float s = ldf(f3b, o, f32);
#pragma unroll
        for (int i = 0; i < 8; ++i) s += p[i] * ldf(f3w, o * 8 + i, f32);
        pos[r * 4 + o] = s;
    }
}

// ---------------------------------------------------------------------------
// win_attn: one block per (window, head); 4 waves x 64 q-tokens. Sel-fused
// QKV (xn read once, acc[3][2][4], (256,3) — mild spill accepted: R10 proved
// it is latency-hidden while a split pass is not). S^T = K Q^T; PV via
// 16x16x16 MFMA consuming P quartets natively. exp2-domain softmax; bias
// rows register-cached (rolling 5-row window, 2 new rows/kb, full unroll).
// XCD-swizzled bid. ONE barrier.
// ---------------------------------------------------------------------------
template <int XN>
__global__ __launch_bounds__(256, 3) void win_attn(
    const void* __restrict__ xv, const bf16_t* __restrict__ xnp,
    const bf16_t* __restrict__ Wp, const float* __restrict__ uu,
    const float* __restrict__ tt, const float* __restrict__ posg,
    const int* __restrict__ flags, void* __restrict__ outv) {
    __shared__ __align__(16) bf16_t k_s[256 * 40];   // q-stage then K [token][d]
    __shared__ __align__(16) bf16_t vT_s[32 * 264];  // V^T [d][token]
    __shared__ __align__(16) float pos_f[31 * 32];   // bias rows padded to 32 f32
    __shared__ float mu_s[XN ? 2 : 256];
    __shared__ float r_s[XN ? 2 : 256];

    const int f32 = flags[0];
    const int tid = threadIdx.x;
    const int lane = tid & 63;
    const int w = tid >> 6;
    const int l15 = lane & 15;
    const int quad = lane >> 4;
    // XCD swizzle: heads of a window map to the same XCD (bid mod 8 equal).
    const int bid = blockIdx.x;
    const int head = (bid >> 3) & 3;
    const int wi = (bid & 7) | ((bid >> 5) << 3);
    const int bi = wi >> 8;
    const int wh = (wi >> 4) & 15, ww = wi & 15;
    const int xbase = bi * (256 * 256 * 128);

    // bias rows padded to stride 32, premultiplied by log2(e)
    for (int r = tid; r < 961; r += 256)
        pos_f[(r / 31) * 32 + (r % 31)] = posg[r * 4 + head] * 1.4426950408889634f;

    if (!XN) {
#pragma unroll
        for (int it = 0; it < 4; ++it) {
            int i = w * 64 + it * 16 + (lane >> 2);
            int gi = xbase + ((wh * 16 + (i >> 4)) * 256 + ww * 16 + (i & 15)) * 128;
            float s = 0.f, s2 = 0.f;
            if (f32) {
                const f32x4* p4 = (const f32x4*)((const float*)xv + gi);
#pragma unroll
                for (int c = 0; c < 4; ++c) {
                    f32x4 a = p4[(c * 4 + (lane & 3)) * 2];
                    f32x4 b = p4[(c * 4 + (lane & 3)) * 2 + 1];
#pragma unroll
                    for (int e = 0; e < 4; ++e) { s += a[e] + b[e]; s2 += a[e] * a[e] + b[e] * b[e]; }
                }
            } else {
                const bf16_t* p = (const bf16_t*)xv + gi;
#pragma unroll
                for (int c = 0; c < 4; ++c) {
                    bf16x8 v = *(const bf16x8*)(p + (c * 4 + (lane & 3)) * 8);
#pragma unroll
                    for (int e = 0; e < 8; ++e) { float f = (float)v[e]; s += f; s2 += f * f; }
                }
            }
            s  += __shfl_xor(s, 1, 4);  s  += __shfl_xor(s, 2, 4);
            s2 += __shfl_xor(s2, 1, 4); s2 += __shfl_xor(s2, 2, 4);
            if ((lane & 3) == 0) {
                float mu = s * (1.f / 128.f);
                mu_s[i] = mu;
                r_s[i] = rsqrtf(s2 * (1.f / 128.f) - mu * mu + 1e-5f);
            }
        }
    }

    // ---- QKV GEMM, sel-FUSED: xn window read once; acc[sel][nt][mt] ----
    int axi[4];
#pragma unroll
    for (int mt = 0; mt < 4; ++mt) {
        int i = w * 64 + mt * 16 + l15;
        axi[mt] = xbase + ((wh * 16 + (i >> 4)) * 256 + ww * 16 + (i & 15)) * 128;
    }
    const float qscale = 0.25503486f;  // log2(e)/sqrt(32)
    bf16x8 qB[4];

    f32x4 acc[3][2][4];
#pragma unroll
    for (int sel = 0; sel < 3; ++sel)
#pragma unroll
        for (int nt = 0; nt < 2; ++nt)
#pragma unroll
            for (int mt = 0; mt < 4; ++mt) acc[sel][nt][mt] = f32x4{0.f, 0.f, 0.f, 0.f};

    const bf16_t* bwBase = Wp + (head * 32 + l15) * 128;
#pragma unroll
    for (int ks = 0; ks < 4; ++ks) {
        int ko = ks * 32 + quad * 8;
        bf16x8 af[4];
        if (XN) {
#pragma unroll
            for (int mt = 0; mt < 4; ++mt)
                af[mt] = *(const bf16x8*)(xnp + axi[mt] + ko);
        } else if (f32) {
#pragma unroll
            for (int mt = 0; mt < 4; ++mt) {
                const float* pp = (const float*)xv + axi[mt] + ko;
                f32x4 u0 = *(const f32x4*)pp;
                f32x4 u1 = *(const f32x4*)(pp + 4);
                bf16x8 t;
#pragma unroll
                for (int e = 0; e < 4; ++e) { t[e] = (bf16_t)u0[e]; t[e + 4] = (bf16_t)u1[e]; }
                af[mt] = t;
            }
        } else {
#pragma unroll
            for (int mt = 0; mt < 4; ++mt)
                af[mt] = *(const bf16x8*)((const bf16_t*)xv + axi[mt] + ko);
        }
#pragma unroll
        for (int sel = 0; sel < 3; ++sel) {
            bf16x8 b0 = *(const bf16x8*)(bwBase + sel * (128 * 128) + ko);
            bf16x8 b1 = *(const bf16x8*)(bwBase + sel * (128 * 128) + 16 * 128 + ko);
#pragma unroll
            for (int mt = 0; mt < 4; ++mt) {
                acc[sel][0][mt] = MFMA16(af[mt], b0, acc[sel][0][mt]);
                acc[sel][1][mt] = MFMA16(af[mt], b1, acc[sel][1][mt]);
            }
        }
    }

    // tt/uu: tiny L2-hot tables; loaded AFTER the MFMA loop to keep peak
    // register pressure down (they are only consumed in the fixup below).
    float tjv[3][2], ujv[3][2];
#pragma unroll
    for (int sel = 0; sel < 3; ++sel)
#pragma unroll
        for (int nt = 0; nt < 2; ++nt) {
            tjv[sel][nt] = tt[sel * 128 + head * 32 + nt * 16 + l15];
            ujv[sel][nt] = XN ? 0.f : uu[sel * 128 + head * 32 + nt * 16 + l15];
        }

    // ---- fixup (LN fold for !XN) + scatter, per sel; q staged then K
    //      overwrites (wave-private rows, program-ordered) ----
#pragma unroll
    for (int sel = 0; sel < 3; ++sel) {
#pragma unroll
        for (int mt = 0; mt < 4; ++mt) {
            int tok0 = w * 64 + mt * 16 + quad * 4;
#pragma unroll
            for (int nt = 0; nt < 2; ++nt) {
                int d = nt * 16 + l15;
                float vv[4];
#pragma unroll
                for (int rg = 0; rg < 4; ++rg) {
                    if (XN) vv[rg] = acc[sel][nt][mt][rg] + tjv[sel][nt];
                    else {
                        int token = tok0 + rg;
                        vv[rg] = r_s[token] * (acc[sel][nt][mt][rg] - mu_s[token] * ujv[sel][nt]) + tjv[sel][nt];
                    }
                }
                if (sel == 0) {
#pragma unroll
                    for (int rg = 0; rg < 4; ++rg)
                        k_s[(tok0 + rg) * 40 + d] = (bf16_t)(vv[rg] * qscale);
                } else if (sel == 1) {
#pragma unroll
                    for (int rg = 0; rg < 4; ++rg)
                        k_s[(tok0 + rg) * 40 + d] = (bf16_t)vv[rg];
                } else {
                    bf16x4 h = { (bf16_t)vv[0], (bf16_t)vv[1],
                                 (bf16_t)vv[2], (bf16_t)vv[3] };
                    *(bf16x4*)(vT_s + d * 264 + tok0) = h;
                }
            }
        }
        if (sel == 0) {
#pragma unroll
            for (int qt = 0; qt < 4; ++qt)
                qB[qt] = *(const bf16x8*)(k_s + (w * 64 + qt * 16 + l15) * 40 + quad * 8);
        }
    }
    __syncthreads();  // K / V^T / pos_f visible to all waves

    // ---- kb loop: S^T = K Q^T; P quartets feed 16x16x16 PV directly.
    //      Bias rows register-cached: rolling window of 5 rows (row(qt,nt) =
    //      w*4+qt-nt-2kb+15 spans 5 values; shifts by -2 per kb -> 2 new
    //      rows/kb). Fully unrolled so all rotation indices are static. ----
    f32x4 Oa[2][4];
#pragma unroll
    for (int np = 0; np < 2; ++np)
#pragma unroll
        for (int qt = 0; qt < 4; ++qt) Oa[np][qt] = f32x4{0.f, 0.f, 0.f, 0.f};
    float lsum[4] = {0.f, 0.f, 0.f, 0.f};

    const f32x4 zero4 = {0.f, 0.f, 0.f, 0.f};
    const int pcol = l15 + 12 - quad * 4;  // base col of this lane's 4 bias f32s
    const float* pbase = pos_f + pcol;

    float rvf[5][4];  // rvf[(s+2kb)%5] holds row (w*4+14-2kb)+s
#pragma unroll
    for (int i = 0; i < 5; ++i) {
        const float* pr = pbase + (w * 4 + 14 + i) * 32;
        rvf[i][0] = pr[0]; rvf[i][1] = pr[1]; rvf[i][2] = pr[2]; rvf[i][3] = pr[3];
    }

#pragma unroll
    for (int kb = 0; kb < 8; ++kb) {
        if (kb > 0) {
            const int p0 = (2 * kb) % 5, p1 = (2 * kb + 1) % 5;
            const float* pr0 = pbase + (w * 4 + 14 - 2 * kb) * 32;
            const float* pr1 = pr0 + 32;
            rvf[p0][0] = pr0[0]; rvf[p0][1] = pr0[1]; rvf[p0][2] = pr0[2]; rvf[p0][3] = pr0[3];
            rvf[p1][0] = pr1[0]; rvf[p1][1] = pr1[1]; rvf[p1][2] = pr1[2]; rvf[p1][3] = pr1[3];
        }
        bf16x4 pF[2][4];  // [nt][qt] native P quartets = PV B-frags
#pragma unroll
        for (int nt = 0; nt < 2; ++nt) {
            bf16x8 kf = *(const bf16x8*)(k_s + (kb * 32 + nt * 16 + l15) * 40 + quad * 8);
            f32x4 S[4];
            __builtin_amdgcn_s_setprio(1);
#pragma unroll
            for (int qt = 0; qt < 4; ++qt) S[qt] = MFMA16(kf, qB[qt], zero4);
            __builtin_amdgcn_s_setprio(0);
#pragma unroll
            for (int qt = 0; qt < 4; ++qt) {
                const int ph = (qt - nt + 1 + 2 * kb) % 5;  // logical row qt-nt+1
                float p[4];
                p[0] = fast_exp2(S[qt][0] + rvf[ph][3]);
                p[1] = fast_exp2(S[qt][1] + rvf[ph][2]);
                p[2] = fast_exp2(S[qt][2] + rvf[ph][1]);
                p[3] = fast_exp2(S[qt][3] + rvf[ph][0]);
                lsum[qt] += (p[0] + p[1]) + (p[2] + p[3]);
                bf16x4 h = { (bf16_t)p[0], (bf16_t)p[1], (bf16_t)p[2], (bf16_t)p[3] };
                pF[nt][qt] = h;
            }
        }
#pragma unroll
        for (int np = 0; np < 2; ++np) {
            const bf16_t* vrow = vT_s + (np * 16 + l15) * 264 + kb * 32 + quad * 4;
            bf16x4 vf0 = *(const bf16x4*)vrow;         // nt=0 k-quartet
            bf16x4 vf1 = *(const bf16x4*)(vrow + 16);  // nt=1 k-quartet
            __builtin_amdgcn_s_setprio(1);
#pragma unroll
            for (int qt = 0; qt < 4; ++qt) {
                Oa[np][qt] = mfma_pv(vf0, pF[0][qt], Oa[np][qt]);
                Oa[np][qt] = mfma_pv(vf1, pF[1][qt], Oa[np][qt]);
            }
            __builtin_amdgcn_s_setprio(0);
        }
    }

    // ---- epilogue: reduce lsum, O/l + residual, store (qt-outer so both
    //      64B halves of each 128B line issue adjacently) ----
    float inv[4];
#pragma unroll
    for (int qt = 0; qt < 4; ++qt) {
        float l = lsum[qt];
        l += __shfl_xor(l, 16, 64);
        l += __shfl_xor(l, 32, 64);
        inv[qt] = 1.f / l;
    }
#pragma unroll
    for (int qt = 0; qt < 4; ++qt)
#pragma unroll
        for (int np = 0; np < 2; ++np) {
            int go = xbase + ((wh * 16 + w * 4 + qt) * 256 + ww * 16 + l15) * 128 +
                     head * 32 + np * 16 + quad * 4;
            if (f32) {
                f32x4 res = *(const f32x4*)((const float*)xv + go);
                f32x4 o;
#pragma unroll
                for (int rg = 0; rg < 4; ++rg) o[rg] = Oa[np][qt][rg] * inv[qt] + res[rg];
                *(f32x4*)((float*)outv + go) = o;
            } else {
                bf16x4 res = *(const bf16x4*)((const bf16_t*)xv + go);
                bf16x4 o;
#pragma unroll
                for (int rg = 0; rg < 4; ++rg)
                    o[rg] = (bf16_t)(Oa[np][qt][rg] * inv[qt] + (float)res[rg]);
                *(bf16x4*)((bf16_t*)outv + go) = o;
            }
        }
}

extern "C" void kernel_launch(void* const* d_in, const int* in_sizes, int n_in,
                              void* d_out, int out_size, void* d_ws, size_t ws_size,
                              hipStream_t stream) {
    const void* x   = d_in[0];
    const void* ng  = d_in[1];
    const void* nb  = d_in[2];
    const void* qw  = d_in[3];
    const void* qb  = d_in[4];
    const void* ppw = d_in[5];
    const void* ppb = d_in[6];
    const void* l1g = d_in[7];
    const void* l1b = d_in[8];
    const void* f1w = d_in[9];
    const void* f1b = d_in[10];
    const void* l2g = d_in[11];
    const void* l2b = d_in[12];
    const void* f2w = d_in[13];
    const void* f2b = d_in[14];
    const void* l3g = d_in[15];
    const void* l3b = d_in[16];
    const void* f3w = d_in[17];
    const void* f3b = d_in[18];

    char* ws = (char*)d_ws;
    int*    flags = (int*)ws;                 // @0, 16 B
    bf16_t* Wp    = (bf16_t*)(ws + 16);       // 98304 B
    float*  uu    = (float*)(ws + 98320);     // 1536 B
    float*  tt    = (float*)(ws + 99856);     // 1536 B
    float*  pos   = (float*)(ws + 101392);    // 15376 B
    bf16_t* xn    = (bf16_t*)(ws + 116768);   // 33554432 B
    const int use_xn = (ws_size >= 116768 + 33554432u) ? 1 : 0;

    int prep_grid = use_xn ? 8292 : 100;
    prep_all<<<dim3(prep_grid), dim3(256), 0, stream>>>(
        x, xn, flags, qw, qb, ng, nb, Wp, uu, tt,
        ppw, ppb, l1g, l1b, f1w, f1b, l2g, l2b, f2w, f2b, l3g, l3b,
        f3w, f3b, pos);
    if (use_xn)
        win_attn<1><<<dim3(2048), dim3(256), 0, stream>>>(x, xn, Wp, uu, tt, pos,
                                                          flags, d_out);
    else
        win_attn<0><<<dim3(2048), dim3(256), 0, stream>>>(x, xn, Wp, uu, tt, pos,
                                                          flags, d_out);
}